// Round 2
// baseline (518.692 us; speedup 1.0000x reference)
//
#include <hip/hip_runtime.h>

#define M_TOK 2048
#define KDIM 2048
#define NDIM 1408
#define NEXP 8
#define RROWS (M_TOK * 2)
#define CAP 1024

typedef __attribute__((ext_vector_type(8))) short short8;
typedef __attribute__((ext_vector_type(4))) float f32x4;

__device__ __forceinline__ unsigned short bf16rn(float f) {
    unsigned int u = __builtin_bit_cast(unsigned int, f);
    u += 0x7FFFu + ((u >> 16) & 1u);
    return (unsigned short)(u >> 16);
}
__device__ __forceinline__ unsigned int pk2(float a, float b) {
    return (unsigned int)bf16rn(a) | ((unsigned int)bf16rn(b) << 16);
}

// async global->LDS, 16 B per lane; lds dest must be wave-uniform base
__device__ __forceinline__ void glds16(const void* g, void* l) {
    __builtin_amdgcn_global_load_lds(
        (const __attribute__((address_space(1))) unsigned int*)g,
        (__attribute__((address_space(3))) unsigned int*)l, 16, 0, 0);
}

// ---------------- routing + dispatch (fp32 -> bf16 row copy) ----------------
__global__ void k_route(const float* __restrict__ h, const int* __restrict__ idx,
                        const float* __restrict__ gate, int* __restrict__ cnt,
                        int* __restrict__ tok_of, float* __restrict__ gate_of,
                        unsigned short* __restrict__ bufA) {
    int r = blockIdx.x;
    __shared__ int s_ep;
    if (threadIdx.x == 0) {
        int e = idx[r];
        int p = atomicAdd(&cnt[e], 1);
        tok_of[e * CAP + p] = r >> 1;
        gate_of[e * CAP + p] = gate[r];
        s_ep = e * CAP + p;
    }
    __syncthreads();
    int ep = s_ep;
    const float4* src = (const float4*)(h + (size_t)(r >> 1) * KDIM) + threadIdx.x * 2;
    float4 a = src[0], b = src[1];
    uint4 o;
    o.x = pk2(a.x, a.y); o.y = pk2(a.z, a.w);
    o.z = pk2(b.x, b.y); o.w = pk2(b.z, b.w);
    *((uint4*)(bufA + (size_t)ep * KDIM) + threadIdx.x) = o;
}

// ---------------- fp32 -> bf16 weight conversion (memory-bound) -------------
__global__ void k_cvt(const float* __restrict__ src, unsigned short* __restrict__ dst) {
    int i = blockIdx.x * blockDim.x + threadIdx.x;
    const float4* s = (const float4*)src + (size_t)i * 2;
    float4 a = s[0], b = s[1];
    uint4 o;
    o.x = pk2(a.x, a.y); o.y = pk2(a.z, a.w);
    o.z = pk2(b.x, b.y); o.w = pk2(b.z, b.w);
    ((uint4*)dst)[i] = o;
}

// ---------------- GEMM1: g,u = A @ W^T ; h = silu(min(g,10)) * clip(u) ------
__global__ __launch_bounds__(256, 2)
void k_gemm1(const unsigned short* __restrict__ bufA,
             const unsigned short* __restrict__ gwb,
             const unsigned short* __restrict__ uwb,
             const int* __restrict__ cnt, unsigned short* __restrict__ hbuf) {
    const int e = blockIdx.z;
    const int m0 = blockIdx.y * 128;
    if (m0 >= cnt[e]) return;
    const int n0 = blockIdx.x * 128;

    const unsigned short* A = bufA + (size_t)e * CAP * KDIM;
    const unsigned short* G = gwb + (size_t)e * NDIM * KDIM;
    const unsigned short* U = uwb + (size_t)e * NDIM * KDIM;

    __shared__ unsigned short sA[128 * 32];
    __shared__ unsigned short sG[128 * 32];
    __shared__ unsigned short sU[128 * 32];

    const int tid = threadIdx.x;
    const int lane = tid & 63;
    const int wave = tid >> 6;
    const int wm = (wave >> 1) * 64, wn = (wave & 1) * 64;
    const int q = lane >> 4, l15 = lane & 15;
    const int r4 = lane >> 2, c8 = (lane & 3) * 8;
    const int seg0 = wave * 2;

    f32x4 accG[4][4] = {};
    f32x4 accU[4][4] = {};

    for (int k0 = 0; k0 < KDIM; k0 += 32) {
        __syncthreads();
#pragma unroll
        for (int c = 0; c < 2; c++) {
            int seg = seg0 + c;                // 0..7, wave-uniform
            int row = seg * 16 + r4;           // tile row this lane fetches
            glds16(A + (size_t)(m0 + row) * KDIM + k0 + c8, &sA[seg * 512]);
            glds16(G + (size_t)(n0 + row) * KDIM + k0 + c8, &sG[seg * 512]);
            glds16(U + (size_t)(n0 + row) * KDIM + k0 + c8, &sU[seg * 512]);
        }
        __syncthreads();

        short8 af[4], gf[4], uf[4];
#pragma unroll
        for (int i = 0; i < 4; i++) {
            af[i] = *(const short8*)&sA[(wm + i * 16 + l15) * 32 + q * 8];
            gf[i] = *(const short8*)&sG[(wn + i * 16 + l15) * 32 + q * 8];
            uf[i] = *(const short8*)&sU[(wn + i * 16 + l15) * 32 + q * 8];
        }
#pragma unroll
        for (int i = 0; i < 4; i++)
#pragma unroll
            for (int j = 0; j < 4; j++) {
                accG[i][j] = __builtin_amdgcn_mfma_f32_16x16x32_bf16(af[i], gf[j], accG[i][j], 0, 0, 0);
                accU[i][j] = __builtin_amdgcn_mfma_f32_16x16x32_bf16(af[i], uf[j], accU[i][j], 0, 0, 0);
            }
    }

    unsigned short* H = hbuf + (size_t)e * CAP * NDIM;
#pragma unroll
    for (int i = 0; i < 4; i++)
#pragma unroll
        for (int j = 0; j < 4; j++) {
            int col = n0 + wn + j * 16 + l15;
#pragma unroll
            for (int rg = 0; rg < 4; rg++) {
                int row = m0 + wm + i * 16 + q * 4 + rg;
                float g = accG[i][j][rg];
                float u = accU[i][j][rg];
                g = fminf(g, 10.f);
                u = fminf(fmaxf(u, -10.f), 10.f);
                float hv = g / (1.f + __expf(-g)) * u;
                H[(size_t)row * NDIM + col] = bf16rn(hv);
            }
        }
}

// ---------------- GEMM2: d = h @ dw^T ; out[tok] += gate * d ----------------
__global__ __launch_bounds__(256, 2)
void k_gemm2(const unsigned short* __restrict__ hbuf,
             const unsigned short* __restrict__ dwb, const int* __restrict__ cnt,
             const int* __restrict__ tok_of, const float* __restrict__ gate_of,
             float* __restrict__ out) {
    const int e = blockIdx.z;
    const int cnt_e = cnt[e];
    const int m0 = blockIdx.y * 128;
    if (m0 >= cnt_e) return;
    const int n0 = blockIdx.x * 128;  // over KDIM (output columns)

    const unsigned short* A = hbuf + (size_t)e * CAP * NDIM;
    const unsigned short* B = dwb + (size_t)e * KDIM * NDIM;

    __shared__ unsigned short sA[128 * 32];
    __shared__ unsigned short sB[128 * 32];

    const int tid = threadIdx.x;
    const int lane = tid & 63;
    const int wave = tid >> 6;
    const int wm = (wave >> 1) * 64, wn = (wave & 1) * 64;
    const int q = lane >> 4, l15 = lane & 15;
    const int r4 = lane >> 2, c8 = (lane & 3) * 8;
    const int seg0 = wave * 2;

    f32x4 acc[4][4] = {};

    for (int k0 = 0; k0 < NDIM; k0 += 32) {
        __syncthreads();
#pragma unroll
        for (int c = 0; c < 2; c++) {
            int seg = seg0 + c;
            int row = seg * 16 + r4;
            glds16(A + (size_t)(m0 + row) * NDIM + k0 + c8, &sA[seg * 512]);
            glds16(B + (size_t)(n0 + row) * NDIM + k0 + c8, &sB[seg * 512]);
        }
        __syncthreads();

        short8 af[4], bfr[4];
#pragma unroll
        for (int i = 0; i < 4; i++) {
            af[i] = *(const short8*)&sA[(wm + i * 16 + l15) * 32 + q * 8];
            bfr[i] = *(const short8*)&sB[(wn + i * 16 + l15) * 32 + q * 8];
        }
#pragma unroll
        for (int i = 0; i < 4; i++)
#pragma unroll
            for (int j = 0; j < 4; j++)
                acc[i][j] = __builtin_amdgcn_mfma_f32_16x16x32_bf16(af[i], bfr[j], acc[i][j], 0, 0, 0);
    }

#pragma unroll
    for (int i = 0; i < 4; i++) {
#pragma unroll
        for (int rg = 0; rg < 4; rg++) {
            int row = m0 + wm + i * 16 + q * 4 + rg;
            if (row < cnt_e) {
                int tok = tok_of[e * CAP + row];
                float gt = gate_of[e * CAP + row];
                float* orow = out + (size_t)tok * KDIM + n0 + wn + l15;
#pragma unroll
                for (int j = 0; j < 4; j++)
                    atomicAdd(orow + j * 16, acc[i][j][rg] * gt);
            }
        }
    }
}

extern "C" void kernel_launch(void* const* d_in, const int* in_sizes, int n_in,
                              void* d_out, int out_size, void* d_ws, size_t ws_size,
                              hipStream_t stream) {
    const float* flat_h = (const float*)d_in[0];
    const int* flat_idx = (const int*)d_in[1];
    const float* flat_gate = (const float*)d_in[2];
    const float* gw = (const float*)d_in[3];
    const float* uw = (const float*)d_in[4];
    const float* dwn = (const float*)d_in[5];
    float* out = (float*)d_out;

    char* w = (char*)d_ws;
    int* cnt = (int*)w;                                  // 256 B reserved
    int* tok_of = (int*)(w + 256);                       // 32 KB
    float* gate_of = (float*)(w + 256 + NEXP * CAP * 4); // 32 KB
    // bulk buffers, MiB-aligned
    unsigned short* bufA = (unsigned short*)(w + (1ull << 20));            // 32 MiB
    unsigned short* hbuf = (unsigned short*)(w + (33ull << 20));           // 22 MiB
    unsigned short* gwb  = (unsigned short*)(w + (56ull << 20));           // 44 MiB
    unsigned short* uwb  = (unsigned short*)(w + (100ull << 20));          // 44 MiB
    unsigned short* dwb  = (unsigned short*)(w + (144ull << 20));          // 44 MiB

    hipMemsetAsync(cnt, 0, 256, stream);
    hipMemsetAsync(out, 0, (size_t)M_TOK * KDIM * 4, stream);

    const int welems8 = NEXP * NDIM * KDIM / 8;   // 2,883,584 per tensor
    k_cvt<<<welems8 / 256, 256, 0, stream>>>(gw, gwb);
    k_cvt<<<welems8 / 256, 256, 0, stream>>>(uw, uwb);
    k_cvt<<<welems8 / 256, 256, 0, stream>>>(dwn, dwb);

    k_route<<<RROWS, 256, 0, stream>>>(flat_h, flat_idx, flat_gate, cnt, tok_of, gate_of, bufA);
    k_gemm1<<<dim3(NDIM / 128, CAP / 128, NEXP), 256, 0, stream>>>(bufA, gwb, uwb, cnt, hbuf);
    k_gemm2<<<dim3(KDIM / 128, CAP / 128, NEXP), 256, 0, stream>>>(hbuf, dwb, cnt, tok_of, gate_of, out);
}

// Round 3
// 461.798 us; speedup vs baseline: 1.1232x; 1.1232x over previous
//
#include <hip/hip_runtime.h>

#define M_TOK 2048
#define KDIM 2048
#define NDIM 1408
#define NEXP 8
#define RROWS (M_TOK * 2)
#define CAP 1024

typedef __attribute__((ext_vector_type(8))) short short8;
typedef __attribute__((ext_vector_type(4))) float f32x4;

__device__ __forceinline__ unsigned short bf16rn(float f) {
    unsigned int u = __builtin_bit_cast(unsigned int, f);
    u += 0x7FFFu + ((u >> 16) & 1u);
    return (unsigned short)(u >> 16);
}
__device__ __forceinline__ unsigned int pk2(float a, float b) {
    return (unsigned int)bf16rn(a) | ((unsigned int)bf16rn(b) << 16);
}

// async global->LDS, 16 B per lane; LDS dest wave-uniform base + lane*16
__device__ __forceinline__ void glds16(const void* g, void* l) {
    __builtin_amdgcn_global_load_lds(
        (const __attribute__((address_space(1))) unsigned int*)g,
        (__attribute__((address_space(3))) unsigned int*)l, 16, 0, 0);
}

// ---------------- routing + dispatch (fp32 -> bf16 row copy) ----------------
__global__ void k_route(const float* __restrict__ h, const int* __restrict__ idx,
                        int* __restrict__ cnt, int* __restrict__ slot_of,
                        unsigned short* __restrict__ bufA) {
    int r = blockIdx.x;
    __shared__ int s_ep;
    if (threadIdx.x == 0) {
        int e = idx[r];
        int p = atomicAdd(&cnt[e], 1);
        int ep = e * CAP + p;
        slot_of[r] = ep;
        s_ep = ep;
    }
    __syncthreads();
    int ep = s_ep;
    const float4* src = (const float4*)(h + (size_t)(r >> 1) * KDIM) + threadIdx.x * 2;
    float4 a = src[0], b = src[1];
    uint4 o;
    o.x = pk2(a.x, a.y); o.y = pk2(a.z, a.w);
    o.z = pk2(b.x, b.y); o.w = pk2(b.z, b.w);
    *((uint4*)(bufA + (size_t)ep * KDIM) + threadIdx.x) = o;
}

// ---------------- fp32 -> bf16 conversion of all three weight tensors ------
__global__ void k_cvt3(const float* __restrict__ s0, const float* __restrict__ s1,
                       const float* __restrict__ s2,
                       unsigned short* __restrict__ d0, unsigned short* __restrict__ d1,
                       unsigned short* __restrict__ d2) {
    const float* src = blockIdx.y == 0 ? s0 : (blockIdx.y == 1 ? s1 : s2);
    unsigned short* dst = blockIdx.y == 0 ? d0 : (blockIdx.y == 1 ? d1 : d2);
    int i = blockIdx.x * blockDim.x + threadIdx.x;
    const float4* s = (const float4*)src + (size_t)i * 2;
    float4 a = s[0], b = s[1];
    uint4 o;
    o.x = pk2(a.x, a.y); o.y = pk2(a.z, a.w);
    o.z = pk2(b.x, b.y); o.w = pk2(b.z, b.w);
    ((uint4*)dst)[i] = o;
}

// ---------------- GEMM1: g,u = A @ W^T ; h = silu(min(g,10)) * clip(u) ------
// flat grid, XCD-aware: xcd = expert; all 11 n-blocks of an (m,e) pair on one XCD
__global__ __launch_bounds__(256, 2)
void k_gemm1(const unsigned short* __restrict__ bufA,
             const unsigned short* __restrict__ gwb,
             const unsigned short* __restrict__ uwb,
             const int* __restrict__ cnt, unsigned short* __restrict__ hbuf) {
    const int f = blockIdx.x;
    const int e = f & 7;
    const int t = f >> 3;            // 0..87
    const int n_blk = t % 11;
    const int m_blk = t / 11;        // 0..7
    const int m0 = m_blk * 128;
    if (m0 >= cnt[e]) return;
    const int n0 = n_blk * 128;

    const unsigned short* A = bufA + (size_t)e * CAP * KDIM;
    const unsigned short* G = gwb + (size_t)e * NDIM * KDIM;
    const unsigned short* U = uwb + (size_t)e * NDIM * KDIM;

    __shared__ unsigned short sA[128 * 64];
    __shared__ unsigned short sG[128 * 64];
    __shared__ unsigned short sU[128 * 64];

    const int tid = threadIdx.x;
    const int lane = tid & 63;
    const int wave = tid >> 6;
    const int wm = (wave >> 1) * 64, wn = (wave & 1) * 64;
    const int q = lane >> 4, l15 = lane & 15;
    // DMA source swizzle: lane covers (row_in_seg = lane>>3, cb_global = (lane&7)^(lane>>3&7))
    const int sr = lane >> 3;
    const int scb = (lane & 7) ^ (sr & 7);
    const int xi = l15 & 7;                 // reader xor key
    const int cbl0 = (q ^ xi) * 8;          // kh=0 LDS col offset (shorts)
    const int cbl1 = ((4 + q) ^ xi) * 8;    // kh=1

    f32x4 accG[4][4] = {};
    f32x4 accU[4][4] = {};

    for (int k0 = 0; k0 < KDIM; k0 += 64) {
        __syncthreads();
#pragma unroll
        for (int c = 0; c < 4; c++) {
            int seg = wave * 4 + c;                 // wave-uniform
            int row = seg * 8 + sr;
            glds16(A + (size_t)(m0 + row) * KDIM + k0 + scb * 8, &sA[seg * 512]);
            glds16(G + (size_t)(n0 + row) * KDIM + k0 + scb * 8, &sG[seg * 512]);
            glds16(U + (size_t)(n0 + row) * KDIM + k0 + scb * 8, &sU[seg * 512]);
        }
        __syncthreads();

#pragma unroll
        for (int kh = 0; kh < 2; kh++) {
            const int co = kh ? cbl1 : cbl0;
            short8 af[4], gf[4], uf[4];
#pragma unroll
            for (int i = 0; i < 4; i++) {
                af[i] = *(const short8*)&sA[(wm + i * 16 + l15) * 64 + co];
                gf[i] = *(const short8*)&sG[(wn + i * 16 + l15) * 64 + co];
                uf[i] = *(const short8*)&sU[(wn + i * 16 + l15) * 64 + co];
            }
#pragma unroll
            for (int i = 0; i < 4; i++)
#pragma unroll
                for (int j = 0; j < 4; j++) {
                    accG[i][j] = __builtin_amdgcn_mfma_f32_16x16x32_bf16(af[i], gf[j], accG[i][j], 0, 0, 0);
                    accU[i][j] = __builtin_amdgcn_mfma_f32_16x16x32_bf16(af[i], uf[j], accU[i][j], 0, 0, 0);
                }
        }
    }

    unsigned short* H = hbuf + (size_t)e * CAP * NDIM;
#pragma unroll
    for (int i = 0; i < 4; i++)
#pragma unroll
        for (int j = 0; j < 4; j++) {
            int col = n0 + wn + j * 16 + l15;
#pragma unroll
            for (int rg = 0; rg < 4; rg++) {
                int row = m0 + wm + i * 16 + q * 4 + rg;
                float g = accG[i][j][rg];
                float u = accU[i][j][rg];
                g = fminf(g, 10.f);
                u = fminf(fmaxf(u, -10.f), 10.f);
                float hv = g / (1.f + __expf(-g)) * u;
                H[(size_t)row * NDIM + col] = bf16rn(hv);
            }
        }
}

// ---------------- GEMM2: d = h @ dw^T -> dbuf (fp32, no atomics) ------------
__global__ __launch_bounds__(256, 2)
void k_gemm2(const unsigned short* __restrict__ hbuf,
             const unsigned short* __restrict__ dwb, const int* __restrict__ cnt,
             float* __restrict__ dbuf) {
    const int f = blockIdx.x;
    const int e = f & 7;
    const int t = f >> 3;            // 0..127
    const int n_blk = t & 15;
    const int m_blk = t >> 4;        // 0..7
    const int cnt_e = cnt[e];
    const int m0 = m_blk * 128;
    if (m0 >= cnt_e) return;
    const int n0 = n_blk * 128;      // over KDIM

    const unsigned short* A = hbuf + (size_t)e * CAP * NDIM;
    const unsigned short* B = dwb + (size_t)e * KDIM * NDIM;

    __shared__ unsigned short sA[128 * 64];
    __shared__ unsigned short sB[128 * 64];

    const int tid = threadIdx.x;
    const int lane = tid & 63;
    const int wave = tid >> 6;
    const int wm = (wave >> 1) * 64, wn = (wave & 1) * 64;
    const int q = lane >> 4, l15 = lane & 15;
    const int sr = lane >> 3;
    const int scb = (lane & 7) ^ (sr & 7);
    const int xi = l15 & 7;
    const int cbl0 = (q ^ xi) * 8;
    const int cbl1 = ((4 + q) ^ xi) * 8;

    f32x4 acc[4][4] = {};

    for (int k0 = 0; k0 < NDIM; k0 += 64) {
        __syncthreads();
#pragma unroll
        for (int c = 0; c < 4; c++) {
            int seg = wave * 4 + c;
            int row = seg * 8 + sr;
            glds16(A + (size_t)(m0 + row) * NDIM + k0 + scb * 8, &sA[seg * 512]);
            glds16(B + (size_t)(n0 + row) * NDIM + k0 + scb * 8, &sB[seg * 512]);
        }
        __syncthreads();

#pragma unroll
        for (int kh = 0; kh < 2; kh++) {
            const int co = kh ? cbl1 : cbl0;
            short8 af[4], bfr[4];
#pragma unroll
            for (int i = 0; i < 4; i++) {
                af[i] = *(const short8*)&sA[(wm + i * 16 + l15) * 64 + co];
                bfr[i] = *(const short8*)&sB[(wn + i * 16 + l15) * 64 + co];
            }
#pragma unroll
            for (int i = 0; i < 4; i++)
#pragma unroll
                for (int j = 0; j < 4; j++)
                    acc[i][j] = __builtin_amdgcn_mfma_f32_16x16x32_bf16(af[i], bfr[j], acc[i][j], 0, 0, 0);
        }
    }

    float* D = dbuf + (size_t)e * CAP * KDIM;
#pragma unroll
    for (int i = 0; i < 4; i++) {
#pragma unroll
        for (int rg = 0; rg < 4; rg++) {
            int row = m0 + wm + i * 16 + q * 4 + rg;
            if (row < cnt_e) {
                float* drow = D + (size_t)row * KDIM + n0 + wn + l15;
#pragma unroll
                for (int j = 0; j < 4; j++)
                    drow[j * 16] = acc[i][j][rg];
            }
        }
    }
}

// ---------------- combine: out[tok] = g0*d[slot0] + g1*d[slot1] -------------
__global__ void k_combine(const float* __restrict__ dbuf, const int* __restrict__ slot_of,
                          const float* __restrict__ gate, float* __restrict__ out) {
    int tk = blockIdx.x;
    int s0 = slot_of[2 * tk], s1 = slot_of[2 * tk + 1];
    float g0 = gate[2 * tk], g1 = gate[2 * tk + 1];
    const float4* r0 = (const float4*)(dbuf + (size_t)s0 * KDIM);
    const float4* r1 = (const float4*)(dbuf + (size_t)s1 * KDIM);
    float4* o = (float4*)(out + (size_t)tk * KDIM);
    int i = threadIdx.x * 2;
#pragma unroll
    for (int c = 0; c < 2; c++) {
        float4 a = r0[i + c], b = r1[i + c];
        float4 v;
        v.x = g0 * a.x + g1 * b.x;
        v.y = g0 * a.y + g1 * b.y;
        v.z = g0 * a.z + g1 * b.z;
        v.w = g0 * a.w + g1 * b.w;
        o[i + c] = v;
    }
}

extern "C" void kernel_launch(void* const* d_in, const int* in_sizes, int n_in,
                              void* d_out, int out_size, void* d_ws, size_t ws_size,
                              hipStream_t stream) {
    const float* flat_h = (const float*)d_in[0];
    const int* flat_idx = (const int*)d_in[1];
    const float* flat_gate = (const float*)d_in[2];
    const float* gw = (const float*)d_in[3];
    const float* uw = (const float*)d_in[4];
    const float* dwn = (const float*)d_in[5];
    float* out = (float*)d_out;

    char* w = (char*)d_ws;
    int* cnt = (int*)w;                         // 256 B
    int* slot_of = (int*)(w + 256);             // 16 KB
    unsigned short* bufA = (unsigned short*)(w + 1048576ull);     // 32 MiB
    unsigned short* hbuf = (unsigned short*)(w + 34603008ull);    // 22 MiB
    unsigned short* gwb  = (unsigned short*)(w + 57671680ull);    // 44 MiB
    unsigned short* uwb  = (unsigned short*)(w + 103809024ull);   // 44 MiB
    unsigned short* dwb  = (unsigned short*)(w + 149946368ull);   // 44 MiB -> ends ~187 MiB
    float* dbuf = (float*)(w + 57671680ull);    // aliases gwb/uwb (dead after gemm1), 64 MiB

    hipMemsetAsync(cnt, 0, 256, stream);

    const int welems8 = NEXP * NDIM * KDIM / 8;   // per-tensor float8 groups
    k_cvt3<<<dim3(welems8 / 256, 3), 256, 0, stream>>>(gw, uw, dwn, gwb, uwb, dwb);
    k_route<<<RROWS, 256, 0, stream>>>(flat_h, flat_idx, cnt, slot_of, bufA);
    k_gemm1<<<8 * 11 * 8, 256, 0, stream>>>(bufA, gwb, uwb, cnt, hbuf);
    k_gemm2<<<8 * 16 * 8, 256, 0, stream>>>(hbuf, dwb, cnt, dbuf);
    k_combine<<<M_TOK, 256, 0, stream>>>(dbuf, slot_of, flat_gate, out);
}